// Round 7
// baseline (479.697 us; speedup 1.0000x reference)
//
#include <hip/hip_runtime.h>

#define B_N 16
#define S_N 577
#define D_N 1280
#define H_N 16
#define HD_N 80
#define HALF_N 40
#define M_N 9232
#define M_PAD 9344
#define K_N 1280
#define VT_S 608
#define QSCALE 0.11180339887498949f /* 1/sqrt(80) */

typedef __bf16 bf16_t;
typedef bf16_t bf16x8 __attribute__((ext_vector_type(8)));
typedef float f32x4 __attribute__((ext_vector_type(4)));

__device__ __forceinline__ float bf2f(unsigned short u) {
    union { unsigned int i; float f; } x; x.i = ((unsigned int)u) << 16; return x.f;
}
__device__ __forceinline__ unsigned short f2bf(float f) {
    union { unsigned int i; float f; } x; x.f = f;
    unsigned int r = x.i + 0x7FFFu + ((x.i >> 16) & 1u);
    return (unsigned short)(r >> 16);
}

__device__ __forceinline__ void gld_lds16(const unsigned short* g, unsigned short* l) {
    __builtin_amdgcn_global_load_lds(
        (const __attribute__((address_space(1))) unsigned int*)g,
        (__attribute__((address_space(3))) unsigned int*)l,
        16, 0, 0);
}

// fp32 -> bf16 (RNE), vectorized x4
__global__ __launch_bounds__(256) void cvt_kernel(const float* __restrict__ in,
                                                  unsigned short* __restrict__ out, int n4) {
    int i = blockIdx.x * 256 + threadIdx.x;
    if (i < n4) {
        float4 v = ((const float4*)in)[i];
        ushort4 o;
        o.x = f2bf(v.x); o.y = f2bf(v.y); o.z = f2bf(v.z); o.w = f2bf(v.w);
        ((ushort4*)out)[i] = o;
    }
}

// All 4 weight matrices -> one concatenated bf16 buffer [Wq;Wk;Wv;Wo]
#define W4_N (D_N * K_N / 4) /* 409600 float4 per W */
__global__ __launch_bounds__(256) void cvt4_kernel(
    const float* __restrict__ w0, const float* __restrict__ w1,
    const float* __restrict__ w2, const float* __restrict__ w3,
    unsigned short* __restrict__ out) {
    int i = blockIdx.x * 256 + threadIdx.x;
    if (i >= 4 * W4_N) return;
    int r = i / W4_N, j = i - r * W4_N;
    const float* src = (r == 0) ? w0 : (r == 1) ? w1 : (r == 2) ? w2 : w3;
    float4 v = ((const float4*)src)[j];
    ushort4 o;
    o.x = f2bf(v.x); o.y = f2bf(v.y); o.z = f2bf(v.z); o.w = f2bf(v.w);
    ((ushort4*)out)[i] = o;
}

// ---------------------------------------------------------------------------
// Fused-QKV GEMM, 128x128 tile, BK=32, 4-set LDS ring, prefetch depth 3.
// Per K-step: stage(set t+3) [4 loads] -> vmcnt(12) [waits tile t's 4 loads,
// issued THREE iterations earlier -> ~3 iters of latency cover] -> barrier ->
// compute(set t&3) [8 ds_read_b128 + 16 MFMA] -> barrier.
// LDS 64 KiB (same as R3 kernel -> 2 blocks/CU); swizzle f(r)=(r>>1)&3
// (R5-verified 0 bank conflicts at BK=32).
// grid 30x73, wsel = bx/10 selects q/k/v epilogue.
// ---------------------------------------------------------------------------
__global__ __launch_bounds__(256) void qkv32_kernel(
    const unsigned short* __restrict__ A,
    const unsigned short* __restrict__ Wb,
    const float* __restrict__ b0, const float* __restrict__ b1,
    const float* __restrict__ b2,
    const float* __restrict__ cosb, const float* __restrict__ sinb,
    void* __restrict__ o0, void* __restrict__ o1, void* __restrict__ o2)
{
    __shared__ __align__(16) unsigned short As[4][128 * 32];
    __shared__ __align__(16) unsigned short Bs[4][128 * 32];

    const int tid = threadIdx.x;
    const int wave = tid >> 6, lane = tid & 63;
    const int quad = lane >> 4, n = lane & 15;
    const int wm = wave >> 1, wn = wave & 1;
    const int m0 = blockIdx.y * 128, n0g = blockIdx.x * 128;

    // staging: wave covers rows wave*32..+31; lane -> row (lane>>2), phys
    // 16B-blk (lane&3); LDS linear (lane*16B). Source col-blk pre-swizzled:
    // cb = (lane&3) ^ f(row), f(r) = (r>>1)&3 -> (lane>>3)&3 for both issues
    // (row bases 0 and 16 contribute 0 mod 4 after >>1).
    const int scb = (lane & 3) ^ ((lane >> 3) & 3);

    const unsigned short* gA = A + (size_t)(m0 + wave * 32 + (lane >> 2)) * K_N + scb * 8;
    const unsigned short* gB = Wb + (size_t)(n0g + wave * 32 + (lane >> 2)) * K_N + scb * 8;

    f32x4 acc[4][4] = {};

    auto stage = [&](int s, int kt) {
        unsigned short* lA = &As[s][wave * 1024];   // wave-uniform base
        unsigned short* lB = &Bs[s][wave * 1024];
        const unsigned short* a = gA + kt * 32;
        const unsigned short* b = gB + kt * 32;
        gld_lds16(a, lA);
        gld_lds16(a + 16 * K_N, lA + 512);
        gld_lds16(b, lB);
        gld_lds16(b + 16 * K_N, lB + 512);
    };

    // read: logical blk = quad of row (base + n); stored at quad ^ ((n>>1)&3)
    // (row bases wm*64, mt*16, wn*64, nt*16 are multiples of 8 -> 0 mod 4 after >>1).
    const int sa_blk = (quad ^ ((n >> 1) & 3)) * 8;
    auto compute = [&](int s) {
        bf16x8 af[4], bfr[4];
        #pragma unroll
        for (int nt = 0; nt < 4; ++nt)
            bfr[nt] = *(const bf16x8*)&Bs[s][(wn * 64 + nt * 16 + n) * 32 + sa_blk];
        #pragma unroll
        for (int mt = 0; mt < 4; ++mt)
            af[mt] = *(const bf16x8*)&As[s][(wm * 64 + mt * 16 + n) * 32 + sa_blk];
        #pragma unroll
        for (int mt = 0; mt < 4; ++mt)
            #pragma unroll
            for (int nt = 0; nt < 4; ++nt)
                acc[mt][nt] = __builtin_amdgcn_mfma_f32_16x16x32_bf16(
                    af[mt], bfr[nt], acc[mt][nt], 0, 0, 0);
    };

    // prologue: 3 tiles in flight (12 loads/wave)
    stage(0, 0); stage(1, 1); stage(2, 2);

    // 40 K-steps. Iter t: stage tile t+3 into set (t+3)&3 (set was last
    // computed at t-1 -> protected by trailing barrier); clamp at tail
    // (dummy re-stage of tile 39 into an already-retired set).
    #pragma unroll 4
    for (int t = 0; t < 40; ++t) {
        const int tn = (t + 3 < 40) ? t + 3 : 39;
        stage((t + 3) & 3, tn);                    // 4 loads, 16 in flight
        asm volatile("s_waitcnt vmcnt(12)" ::: "memory");  // tile t landed
        __builtin_amdgcn_s_barrier();              // publish tile t
        compute(t & 3);                            // 12 newer loads still flying
        __builtin_amdgcn_s_barrier();              // reads done -> set reusable
    }
    asm volatile("s_waitcnt vmcnt(0)" ::: "memory");  // retire tail dummies

    const int mbase = m0 + wm * 64;
    const int wsel = blockIdx.x / 10;   // block-uniform: 0=q, 1=k, 2=v
    const float* bias = (wsel == 0) ? b0 : (wsel == 1) ? b1 : b2;
    unsigned short* out =
        (unsigned short*)((wsel == 0) ? o0 : (wsel == 1) ? o1 : o2);
    const int nloc = n0g - wsel * 1280 + wn * 64;
    const bool evn = (n & 1) == 0;
    #pragma unroll
    for (int nt = 0; nt < 4; ++nt) {
        const int ncol = nloc + nt * 16 + n;
        const int h = ncol / HD_N, hd = ncol - h * HD_N;
        const float bv = bias[ncol];
        #pragma unroll
        for (int mt = 0; mt < 4; ++mt)
            #pragma unroll
            for (int r = 0; r < 4; ++r) {
                int mrow = mbase + mt * 16 + quad * 4 + r;
                int b = mrow / S_N, s = mrow - b * S_N;
                float v = acc[mt][nt][r] + bv;
                if (wsel == 2) {
                    if (mrow < M_N)
                        out[((size_t)(b * H_N + h) * HD_N + hd) * VT_S + s] = f2bf(v);
                } else {
                    float pv = __shfl_xor(v, 1);  // paired column (ncol^1)
                    float c  = cosb[s * HALF_N + (hd >> 1)];
                    float sn = sinb[s * HALF_N + (hd >> 1)];
                    float res = evn ? (v * c - pv * sn) : (pv * sn + v * c);
                    if (wsel == 0) res *= QSCALE;
                    if (mrow < M_N)
                        out[((size_t)(b * H_N + h) * S_N + s) * HD_N + hd] = f2bf(res);
                }
            }
    }
}

// MFMA GEMM, BK=64, XOR-swizzled LDS, double-buffer with counted vmcnt
// (R3-verified). Out-projection: fp32 (B,S,D) output (grid 10x73).
__global__ __launch_bounds__(256) void mgemm64_kernel(
    const unsigned short* __restrict__ A,
    const unsigned short* __restrict__ Wb,
    const float* __restrict__ b0,
    void* __restrict__ o0)
{
    __shared__ __align__(16) unsigned short As[2][128 * 64];
    __shared__ __align__(16) unsigned short Bs[2][128 * 64];

    const int tid = threadIdx.x;
    const int wave = tid >> 6, lane = tid & 63;
    const int quad = lane >> 4, n = lane & 15;
    const int wm = wave >> 1, wn = wave & 1;
    const int m0 = blockIdx.y * 128, n0g = blockIdx.x * 128;

    const int srow = lane >> 3;
    const int scol = (((lane & 7) ^ srow) * 8);

    const unsigned short* gA = A + (size_t)(m0 + wave * 32 + srow) * K_N + scol;
    const unsigned short* gB = Wb + (size_t)(n0g + wave * 32 + srow) * K_N + scol;
    const int lofs = wave * 32 * 64;

    f32x4 acc[4][4] = {};

    auto stage = [&](int pp, int k0) {
        unsigned short* lA = &As[pp][lofs];
        unsigned short* lB = &Bs[pp][lofs];
        #pragma unroll
        for (int i = 0; i < 4; ++i) {
            gld_lds16(gA + k0 + i * 8 * K_N, lA + i * 512);
            gld_lds16(gB + k0 + i * 8 * K_N, lB + i * 512);
        }
    };

    auto compute = [&](int pp) {
        #pragma unroll
        for (int kk = 0; kk < 2; ++kk) {
            const int sa = ((((kk << 2) | quad) ^ (n & 7)) * 8);
            bf16x8 af[4], bfr[4];
            #pragma unroll
            for (int mt = 0; mt < 4; ++mt)
                af[mt] = *(const bf16x8*)&As[pp][(wm * 64 + mt * 16 + n) * 64 + sa];
            #pragma unroll
            for (int nt = 0; nt < 4; ++nt)
                bfr[nt] = *(const bf16x8*)&Bs[pp][(wn * 64 + nt * 16 + n) * 64 + sa];
            #pragma unroll
            for (int mt = 0; mt < 4; ++mt)
                #pragma unroll
                for (int nt = 0; nt < 4; ++nt)
                    acc[mt][nt] = __builtin_amdgcn_mfma_f32_16x16x32_bf16(
                        af[mt], bfr[nt], acc[mt][nt], 0, 0, 0);
        }
    };

    stage(0, 0);

    #pragma unroll 2
    for (int t = 0; t < 19; ++t) {
        const int pp = t & 1;
        stage(pp ^ 1, (t + 1) * 64);
        asm volatile("s_waitcnt vmcnt(8)" ::: "memory");
        __builtin_amdgcn_s_barrier();
        compute(pp);
        __builtin_amdgcn_s_barrier();
    }
    asm volatile("s_waitcnt vmcnt(0)" ::: "memory");
    __builtin_amdgcn_s_barrier();
    compute(1);

    const int mbase = m0 + wm * 64;
    const int nbase = n0g + wn * 64;
    float* outp = (float*)o0;
    #pragma unroll
    for (int mt = 0; mt < 4; ++mt)
        #pragma unroll
        for (int nt = 0; nt < 4; ++nt) {
            const int ncol = nbase + nt * 16 + n;
            const float bv = b0[ncol];
            #pragma unroll
            for (int r = 0; r < 4; ++r) {
                int mrow = mbase + mt * 16 + quad * 4 + r;
                if (mrow < M_N)
                    outp[(size_t)mrow * D_N + ncol] = acc[mt][nt][r] + bv;
            }
        }
}

// MFMA flash attention v2 (R3-verified, 113 us): 32 q-rows per wave,
// no-max softmax, row-sum via ones-column MFMA, ping-pong P LDS,
// XCD-swizzled grid (1280 blocks = 5/CU).
__global__ __launch_bounds__(256) void fattn_kernel(
    const unsigned short* __restrict__ qb,
    const unsigned short* __restrict__ kb,
    const unsigned short* __restrict__ vt,
    unsigned short* __restrict__ attn)
{
    __shared__ __align__(16) unsigned short Plds[4][2][2][16 * 32]; // wave/pp/chain

    const int tid = threadIdx.x;
    const int wave = tid >> 6, lane = tid & 63;
    const int quad = lane >> 4, n = lane & 15;

    const int bid = blockIdx.x;
    const int xcd = bid & 7, t = bid >> 3;      // t: 0..159
    const int qt = t % 5, hl = t / 5;           // hl: 0..31
    const int bh = hl * 8 + xcd;
    const int q0 = qt * 128 + wave * 32;        // 32 rows per wave

    const bf16x8 zf{};
    const unsigned short* qrow0 = qb + ((size_t)bh * S_N + q0 + n) * HD_N;
    const unsigned short* qrow1 = qrow0 + 16 * HD_N;
    bf16x8 aq00 = *(const bf16x8*)(qrow0 + quad * 8);
    bf16x8 aq01 = *(const bf16x8*)(qrow0 + 32 + quad * 8);
    bf16x8 aq02 = (quad < 2) ? *(const bf16x8*)(qrow0 + 64 + quad * 8) : zf;
    bf16x8 aq10 = *(const bf16x8*)(qrow1 + quad * 8);
    bf16x8 aq11 = *(const bf16x8*)(qrow1 + 32 + quad * 8);
    bf16x8 aq12 = (quad < 2) ? *(const bf16x8*)(qrow1 + 64 + quad * 8) : zf;

    // ones B-fragment: column 0 = 1 -> o[5][r] = sum_k P[r][k]
    const bf16_t one = (bf16_t)1.0f;
    const bf16x8 vones_all = {one, one, one, one, one, one, one, one};
    const bf16x8 vones = (n == 0) ? vones_all : zf;

    f32x4 o0[6] = {};
    f32x4 o1[6] = {};

    const unsigned short* kbase = kb + (size_t)bh * S_N * HD_N;
    const unsigned short* vbase = vt + (size_t)bh * HD_N * VT_S;

    #pragma unroll 2
    for (int t0 = 0; t0 < 608; t0 += 32) {
        const int pp = (t0 >> 5) & 1;
        unsigned short* pl0 = &Plds[wave][pp][0][0];
        unsigned short* pl1 = &Plds[wave][pp][1][0];

        // ---- shared K fragments for this 32-key slab ----
        const unsigned short* krA = kbase + (size_t)(t0 + n) * HD_N;
        const unsigned short* krB = krA + 16 * HD_N;
        bf16x8 bA0 = *(const bf16x8*)(krA + quad * 8);
        bf16x8 bA1 = *(const bf16x8*)(krA + 32 + quad * 8);
        bf16x8 bA2 = (quad < 2) ? *(const bf16x8*)(krA + 64 + quad * 8) : zf;
        bf16x8 bB0 = *(const bf16x8*)(krB + quad * 8);
        bf16x8 bB1 = *(const bf16x8*)(krB + 32 + quad * 8);
        bf16x8 bB2 = (quad < 2) ? *(const bf16x8*)(krB + 64 + quad * 8) : zf;

        // ---- QK^T both chains ----
        f32x4 c00{}, c01{}, c10{}, c11{};
        c00 = __builtin_amdgcn_mfma_f32_16x16x32_bf16(aq00, bA0, c00, 0, 0, 0);
        c00 = __builtin_amdgcn_mfma_f32_16x16x32_bf16(aq01, bA1, c00, 0, 0, 0);
        c00 = __builtin_amdgcn_mfma_f32_16x16x32_bf16(aq02, bA2, c00, 0, 0, 0);
        c01 = __builtin_amdgcn_mfma_f32_16x16x32_bf16(aq00, bB0, c01, 0, 0, 0);
        c01 = __builtin_amdgcn_mfma_f32_16x16x32_bf16(aq01, bB1, c01, 0, 0, 0);
        c01 = __builtin_amdgcn_mfma_f32_16x16x32_bf16(aq02, bB2, c01, 0, 0, 0);
        c10 = __builtin_amdgcn_mfma_f32_16x16x32_bf16(aq10, bA0, c10, 0, 0, 0);
        c10 = __builtin_amdgcn_mfma_f32_16x16x32_bf16(aq11, bA1, c10, 0, 0, 0);
        c10 = __builtin_amdgcn_mfma_f32_16x16x32_bf16(aq12, bA2, c10, 0, 0, 0);
        c11 = __builtin_amdgcn_mfma_f32_16x16x32_bf16(aq10, bB0, c11, 0, 0, 0);
        c11 = __builtin_amdgcn_mfma_f32_16x16x32_bf16(aq11, bB1, c11, 0, 0, 0);
        c11 = __builtin_amdgcn_mfma_f32_16x16x32_bf16(aq12, bB2, c11, 0, 0, 0);

        const bool mA = (t0 + n) >= S_N;
        const bool mB = (t0 + 16 + n) >= S_N;

        #pragma unroll
        for (int r = 0; r < 4; ++r) {
            float p00 = mA ? 0.0f : __expf(c00[r]);
            float p01 = mB ? 0.0f : __expf(c01[r]);
            float p10 = mA ? 0.0f : __expf(c10[r]);
            float p11 = mB ? 0.0f : __expf(c11[r]);
            pl0[(quad * 4 + r) * 32 + n]      = f2bf(p00);
            pl0[(quad * 4 + r) * 32 + 16 + n] = f2bf(p01);
            pl1[(quad * 4 + r) * 32 + n]      = f2bf(p10);
            pl1[(quad * 4 + r) * 32 + 16 + n] = f2bf(p11);
        }

        bf16x8 ap0 = *(const bf16x8*)(pl0 + n * 32 + quad * 8);
        bf16x8 ap1 = *(const bf16x8*)(pl1 + n * 32 + quad * 8);

        #pragma unroll
        for (int nt = 0; nt < 5; ++nt) {
            const unsigned short* vr = vbase + (size_t)(nt * 16 + n) * VT_S + t0 + quad * 8;
            bf16x8 bv = *(const bf16x8*)vr;
            o0[nt] = __builtin_amdgcn_mfma_f32_16x16x32_bf16(ap0, bv, o0[nt], 0, 0, 0);
            o1[nt] = __builtin_amdgcn_mfma_f32_16x16x32_bf16(ap1, bv, o1[nt], 0, 0, 0);
        }
        o0[5] = __builtin_amdgcn_mfma_f32_16x16x32_bf16(ap0, vones, o0[5], 0, 0, 0);
        o1[5] = __builtin_amdgcn_mfma_f32_16x16x32_bf16(ap1, vones, o1[5], 0, 0, 0);
    }

    const int b = bh >> 4, h = bh & 15;
    #pragma unroll
    for (int r = 0; r < 4; ++r) {
        float l0 = __shfl(o0[5][r], lane & 48);   // col-0 lane of this quad
        float l1 = __shfl(o1[5][r], lane & 48);
        float linv0 = 1.0f / l0, linv1 = 1.0f / l1;
        int s0 = q0 + quad * 4 + r;
        int s1 = s0 + 16;
        #pragma unroll
        for (int nt = 0; nt < 5; ++nt) {
            if (s0 < S_N)
                attn[((size_t)b * S_N + s0) * D_N + h * HD_N + nt * 16 + n] =
                    f2bf(o0[nt][r] * linv0);
            if (s1 < S_N)
                attn[((size_t)b * S_N + s1) * D_N + h * HD_N + nt * 16 + n] =
                    f2bf(o1[nt][r] * linv1);
        }
    }
}

extern "C" void kernel_launch(void* const* d_in, const int* in_sizes, int n_in,
                              void* d_out, int out_size, void* d_ws, size_t ws_size,
                              hipStream_t stream) {
    const float* hs = (const float*)d_in[0];
    const float* fc = (const float*)d_in[1];
    const float* fs = (const float*)d_in[2];
    const float* Wq = (const float*)d_in[3];
    const float* bq = (const float*)d_in[4];
    const float* Wk = (const float*)d_in[5];
    const float* bk = (const float*)d_in[6];
    const float* Wv = (const float*)d_in[7];
    const float* bv = (const float*)d_in[8];
    const float* Wo = (const float*)d_in[9];
    const float* bo = (const float*)d_in[10];
    float* out = (float*)d_out;

    char* ws = (char*)d_ws;
    size_t off = 0;
    auto alloc = [&](size_t bytes) {
        char* p = ws + off; off += (bytes + 255) & ~(size_t)255; return p;
    };
    unsigned short* hsb  = (unsigned short*)alloc((size_t)M_PAD * K_N * 2); // aliased as 'at'
    unsigned short* qb   = (unsigned short*)alloc((size_t)M_N * K_N * 2 + 32768);
    unsigned short* kb   = (unsigned short*)alloc((size_t)M_N * K_N * 2 + 32768);
    unsigned short* vt   = (unsigned short*)alloc((size_t)B_N * H_N * HD_N * VT_S * 2);
    unsigned short* Wall = (unsigned short*)alloc((size_t)4 * D_N * K_N * 2);

    const int HS4 = M_N * K_N / 4;   // 2,954,240
    dim3 blk(256);

    cvt_kernel<<<(HS4 + 255) / 256, blk, 0, stream>>>(hs, hsb, HS4);
    cvt4_kernel<<<(4 * W4_N + 255) / 256, blk, 0, stream>>>(Wq, Wk, Wv, Wo, Wall);

    // fused QKV: N = 3840 columns over concatenated [Wq;Wk;Wv], depth-3 pipeline
    qkv32_kernel<<<dim3(30, 73), blk, 0, stream>>>(
        hsb, Wall, bq, bk, bv, fc, fs, qb, kb, vt);

    fattn_kernel<<<dim3(1280), blk, 0, stream>>>(qb, kb, vt, hsb /*= at*/);

    mgemm64_kernel<<<dim3(10, 73), blk, 0, stream>>>(
        hsb, Wall + 3 * (size_t)D_N * K_N, bo, out);
}

// Round 8
// 455.416 us; speedup vs baseline: 1.0533x; 1.0533x over previous
//
#include <hip/hip_runtime.h>

#define B_N 16
#define S_N 577
#define D_N 1280
#define H_N 16
#define HD_N 80
#define HALF_N 40
#define M_N 9232
#define M_PAD 9344
#define M_PAD2 9472
#define K_N 1280
#define VT_S 608
#define QSCALE 0.11180339887498949f /* 1/sqrt(80) */

typedef __bf16 bf16_t;
typedef bf16_t bf16x8 __attribute__((ext_vector_type(8)));
typedef float f32x4 __attribute__((ext_vector_type(4)));

__device__ __forceinline__ float bf2f(unsigned short u) {
    union { unsigned int i; float f; } x; x.i = ((unsigned int)u) << 16; return x.f;
}
__device__ __forceinline__ unsigned short f2bf(float f) {
    union { unsigned int i; float f; } x; x.f = f;
    unsigned int r = x.i + 0x7FFFu + ((x.i >> 16) & 1u);
    return (unsigned short)(r >> 16);
}

__device__ __forceinline__ void gld_lds16(const unsigned short* g, unsigned short* l) {
    __builtin_amdgcn_global_load_lds(
        (const __attribute__((address_space(1))) unsigned int*)g,
        (__attribute__((address_space(3))) unsigned int*)l,
        16, 0, 0);
}

// fp32 -> bf16 (RNE), vectorized x4
__global__ __launch_bounds__(256) void cvt_kernel(const float* __restrict__ in,
                                                  unsigned short* __restrict__ out, int n4) {
    int i = blockIdx.x * 256 + threadIdx.x;
    if (i < n4) {
        float4 v = ((const float4*)in)[i];
        ushort4 o;
        o.x = f2bf(v.x); o.y = f2bf(v.y); o.z = f2bf(v.z); o.w = f2bf(v.w);
        ((ushort4*)out)[i] = o;
    }
}

// All 4 weight matrices -> one concatenated bf16 buffer [Wq;Wk;Wv;Wo]
#define W4_N (D_N * K_N / 4) /* 409600 float4 per W */
__global__ __launch_bounds__(256) void cvt4_kernel(
    const float* __restrict__ w0, const float* __restrict__ w1,
    const float* __restrict__ w2, const float* __restrict__ w3,
    unsigned short* __restrict__ out) {
    int i = blockIdx.x * 256 + threadIdx.x;
    if (i >= 4 * W4_N) return;
    int r = i / W4_N, j = i - r * W4_N;
    const float* src = (r == 0) ? w0 : (r == 1) ? w1 : (r == 2) ? w2 : w3;
    float4 v = ((const float4*)src)[j];
    ushort4 o;
    o.x = f2bf(v.x); o.y = f2bf(v.y); o.z = f2bf(v.z); o.w = f2bf(v.w);
    ((ushort4*)out)[i] = o;
}

// ---------------------------------------------------------------------------
// 256x256 8-phase fused-QKV GEMM (T2+T3+T4+T5) — R4 schedule (refcheck'd)
// with the CORRECTED swizzle (R5-verified 0-conflict): f(r) = (r>>1)&3.
// R4's f(r)=r&3 collapsed to {0,2} on even fragment rows -> 4-way conflict
// on every ds_read_b128 (8.5M conflicts). Corrected: store phys blk
// cb ^ ((r>>1)&3); read (quad ^ ((n>>1)&3)).
// 512 threads = 8 waves (2M x 4N); per-wave output 128x64 -> acc[8][4].
// BK=64 split into 2 K-halves of 32; LDS: [2 sets][2 khalves] per matrix.
// Per phase: 4-8 ds_read_b128 + 1 half-tile stage (2 gld_lds) + 16 MFMA
// (setprio-wrapped). vmcnt(8) at end of even phases only (never 0 in-loop).
// ---------------------------------------------------------------------------
#define PHASE_MFMA(AFR, BFR, MB) do {                                          \
    __builtin_amdgcn_s_setprio(1);                                             \
    _Pragma("unroll")                                                          \
    for (int mf_ = 0; mf_ < 4; ++mf_) {                                        \
        _Pragma("unroll")                                                      \
        for (int nf_ = 0; nf_ < 4; ++nf_)                                      \
            acc[(MB) + mf_][nf_] = __builtin_amdgcn_mfma_f32_16x16x32_bf16(    \
                (AFR)[mf_], (BFR)[nf_], acc[(MB) + mf_][nf_], 0, 0, 0);        \
    }                                                                          \
    __builtin_amdgcn_s_setprio(0);                                             \
} while (0)

#define BARRIER() do {                                                         \
    asm volatile("" ::: "memory");                                             \
    __builtin_amdgcn_s_barrier();                                              \
    __builtin_amdgcn_sched_barrier(0);                                         \
    asm volatile("" ::: "memory");                                             \
} while (0)

#define VMCNT8() do { asm volatile("s_waitcnt vmcnt(8)" ::: "memory"); } while (0)

// one K-half = 2 phases: {bfr+afL reads, stage ST_ODD, 16 MFMA, bar} then
// {afH reads, stage ST_EVEN, 16 MFMA, vmcnt(8), bar}
#define KHALF(S, KK, ST_ODD, ST_EVEN) do {                                     \
    bf16x8 bfr[4], af[4];                                                      \
    _Pragma("unroll")                                                          \
    for (int f_ = 0; f_ < 4; ++f_) bfr[f_] = rdB(S, KK, f_);                   \
    _Pragma("unroll")                                                          \
    for (int f_ = 0; f_ < 4; ++f_) af[f_] = rdA(S, KK, f_);                    \
    ST_ODD;                                                                    \
    PHASE_MFMA(af, bfr, 0);                                                    \
    BARRIER();                                                                 \
    _Pragma("unroll")                                                          \
    for (int f_ = 0; f_ < 4; ++f_) af[f_] = rdA(S, KK, 4 + f_);                \
    ST_EVEN;                                                                   \
    PHASE_MFMA(af, bfr, 4);                                                    \
    VMCNT8();                                                                  \
    BARRIER();                                                                 \
} while (0)

__global__ __launch_bounds__(512) void mgemm256_kernel(
    const unsigned short* __restrict__ A,
    const unsigned short* __restrict__ Wb,
    const float* __restrict__ b0, const float* __restrict__ b1,
    const float* __restrict__ b2,
    const float* __restrict__ cosb, const float* __restrict__ sinb,
    void* __restrict__ o0, void* __restrict__ o1, void* __restrict__ o2)
{
    extern __shared__ unsigned short smem[];  // 128 KiB dynamic LDS
    unsigned short* const Asb = smem;             // [set][kk][256*32]
    unsigned short* const Bsb = smem + 4 * 8192;  // [set][kk][256*32]

    const int tid = threadIdx.x;
    const int wave = tid >> 6, lane = tid & 63;
    const int quad = lane >> 4, n = lane & 15;
    const int wm = wave >> 2, wn = wave & 3;
    const int m0 = blockIdx.y * 256, n0g = blockIdx.x * 256;

    // staging: thread covers row (wave*16 + lane>>2), phys 16B-blk (lane&3);
    // source col-blk pre-swizzled: cb = (lane&3) ^ f(row), f(r)=(r>>1)&3
    // -> (lane>>3)&3 (wave*16 contributes 0 mod 4 after >>1).  [R5-verified]
    const int srow = wave * 16 + (lane >> 2);
    const int scb  = (lane & 3) ^ ((lane >> 3) & 3);

    const unsigned short* gA = A  + (size_t)(m0  + srow) * K_N + scb * 8;
    const unsigned short* gB = Wb + (size_t)(n0g + srow) * K_N + scb * 8;

    f32x4 acc[8][4] = {};

    auto stA = [&](int s, int h, int kt) {
        unsigned short* l = Asb + (s * 2 + h) * 8192 + wave * 512;  // wave-uniform
        const unsigned short* g = gA + kt * 64 + h * 32;
        gld_lds16(g, l);
        gld_lds16(g + (size_t)128 * K_N, l + 4096);
    };
    auto stB = [&](int s, int h, int kt) {
        unsigned short* l = Bsb + (s * 2 + h) * 8192 + wave * 512;
        const unsigned short* g = gB + kt * 64 + h * 32;
        gld_lds16(g, l);
        gld_lds16(g + (size_t)128 * K_N, l + 4096);
    };

    // read: logical blk = quad of row (base + n), base multiple of 16 ->
    // f(row) = (n>>1)&3.  [corrected from R4's (n&3)]
    const int sa_blk = (quad ^ ((n >> 1) & 3)) * 8;
    auto rdA = [&](int s, int kk, int mf) {
        return *(const bf16x8*)&Asb[(s * 2 + kk) * 8192 +
                                    (wm * 128 + mf * 16 + n) * 32 + sa_blk];
    };
    auto rdB = [&](int s, int kk, int nf) {
        return *(const bf16x8*)&Bsb[(s * 2 + kk) * 8192 +
                                    (wn * 64 + nf * 16 + n) * 32 + sa_blk];
    };

    // prologue: 6 halves (12 loads) in steady-state order; P1/P2 of iter 0
    // stage the remaining A(1)k1 / B(1)k1.
    stA(0, 0, 0); stB(0, 0, 0); stA(0, 1, 0); stB(0, 1, 0); stA(1, 0, 1); stB(1, 0, 1);
    VMCNT8();   // oldest 4 loads (A0k0,B0k0) landed; 8 younger in flight
    BARRIER();

    // 20 K-tiles = 10 iterations x {even tile -> set 0, odd tile -> set 1}
    #pragma unroll 1
    for (int i = 0; i < 10; ++i) {
        const int tb  = 2 * i + 1;
        const int ta2 = (2 * i + 2 > 19) ? 19 : 2 * i + 2;  // clamped (dummy re-stage at tail)
        const int tb2 = (2 * i + 3 > 19) ? 19 : 2 * i + 3;
        KHALF(0, 0, stA(1, 1, tb),  stB(1, 1, tb));   // P1,P2: compute a/kk0
        KHALF(0, 1, stA(0, 0, ta2), stB(0, 0, ta2));  // P3,P4: compute a/kk1
        KHALF(1, 0, stA(0, 1, ta2), stB(0, 1, ta2));  // P5,P6: compute b/kk0
        KHALF(1, 1, stA(1, 0, tb2), stB(1, 0, tb2));  // P7,P8: compute b/kk1
    }
    asm volatile("s_waitcnt vmcnt(0)" ::: "memory");  // drain tail dummies

    // ---- fused QKV epilogue: wsel = bx/5 (5 col-tiles per 1280-wide W) ----
    const int wsel = blockIdx.x / 5;  // block-uniform: 0=q, 1=k, 2=v
    const float* bias = (wsel == 0) ? b0 : (wsel == 1) ? b1 : b2;
    unsigned short* out =
        (unsigned short*)((wsel == 0) ? o0 : (wsel == 1) ? o1 : o2);
    const int nloc0 = n0g - wsel * 1280 + wn * 64;
    const bool evn = (n & 1) == 0;

    #pragma unroll
    for (int mf = 0; mf < 8; ++mf) {
        #pragma unroll
        for (int r = 0; r < 4; ++r) {
            const int mrow = m0 + wm * 128 + mf * 16 + quad * 4 + r;
            const int b = mrow / S_N, s = mrow - b * S_N;
            const bool ok = mrow < M_N;
            #pragma unroll
            for (int nf = 0; nf < 4; ++nf) {
                const int ncol = nloc0 + nf * 16 + n;
                const int h = ncol / HD_N, hd = ncol - h * HD_N;
                float v = acc[mf][nf][r] + bias[ncol];
                if (wsel == 2) {
                    if (ok)
                        out[((size_t)(b * H_N + h) * HD_N + hd) * VT_S + s] = f2bf(v);
                } else {
                    float pv = __shfl_xor(v, 1);  // paired column (ncol^1)
                    float c  = cosb[s * HALF_N + (hd >> 1)];
                    float sn = sinb[s * HALF_N + (hd >> 1)];
                    float res = evn ? (v * c - pv * sn) : (pv * sn + v * c);
                    if (wsel == 0) res *= QSCALE;
                    if (ok)
                        out[((size_t)(b * H_N + h) * S_N + s) * HD_N + hd] = f2bf(res);
                }
            }
        }
    }
}

// MFMA GEMM, BK=64, XOR-swizzled LDS, double-buffer with counted vmcnt
// (R3-verified). Out-projection: fp32 (B,S,D) output (grid 10x73).
__global__ __launch_bounds__(256) void mgemm64_kernel(
    const unsigned short* __restrict__ A,
    const unsigned short* __restrict__ Wb,
    const float* __restrict__ b0,
    void* __restrict__ o0)
{
    __shared__ __align__(16) unsigned short As[2][128 * 64];
    __shared__ __align__(16) unsigned short Bs[2][128 * 64];

    const int tid = threadIdx.x;
    const int wave = tid >> 6, lane = tid & 63;
    const int quad = lane >> 4, n = lane & 15;
    const int wm = wave >> 1, wn = wave & 1;
    const int m0 = blockIdx.y * 128, n0g = blockIdx.x * 128;

    const int srow = lane >> 3;
    const int scol = (((lane & 7) ^ srow) * 8);

    const unsigned short* gA = A + (size_t)(m0 + wave * 32 + srow) * K_N + scol;
    const unsigned short* gB = Wb + (size_t)(n0g + wave * 32 + srow) * K_N + scol;
    const int lofs = wave * 32 * 64;

    f32x4 acc[4][4] = {};

    auto stage = [&](int pp, int k0) {
        unsigned short* lA = &As[pp][lofs];
        unsigned short* lB = &Bs[pp][lofs];
        #pragma unroll
        for (int i = 0; i < 4; ++i) {
            gld_lds16(gA + k0 + i * 8 * K_N, lA + i * 512);
            gld_lds16(gB + k0 + i * 8 * K_N, lB + i * 512);
        }
    };

    auto compute = [&](int pp) {
        #pragma unroll
        for (int kk = 0; kk < 2; ++kk) {
            const int sa = ((((kk << 2) | quad) ^ (n & 7)) * 8);
            bf16x8 af[4], bfr[4];
            #pragma unroll
            for (int mt = 0; mt < 4; ++mt)
                af[mt] = *(const bf16x8*)&As[pp][(wm * 64 + mt * 16 + n) * 64 + sa];
            #pragma unroll
            for (int nt = 0; nt < 4; ++nt)
                bfr[nt] = *(const bf16x8*)&Bs[pp][(wn * 64 + nt * 16 + n) * 64 + sa];
            #pragma unroll
            for (int mt = 0; mt < 4; ++mt)
                #pragma unroll
                for (int nt = 0; nt < 4; ++nt)
                    acc[mt][nt] = __builtin_amdgcn_mfma_f32_16x16x32_bf16(
                        af[mt], bfr[nt], acc[mt][nt], 0, 0, 0);
        }
    };

    stage(0, 0);

    #pragma unroll 2
    for (int t = 0; t < 19; ++t) {
        const int pp = t & 1;
        stage(pp ^ 1, (t + 1) * 64);
        asm volatile("s_waitcnt vmcnt(8)" ::: "memory");
        __builtin_amdgcn_s_barrier();
        compute(pp);
        __builtin_amdgcn_s_barrier();
    }
    asm volatile("s_waitcnt vmcnt(0)" ::: "memory");
    __builtin_amdgcn_s_barrier();
    compute(1);

    const int mbase = m0 + wm * 64;
    const int nbase = n0g + wn * 64;
    float* outp = (float*)o0;
    #pragma unroll
    for (int mt = 0; mt < 4; ++mt)
        #pragma unroll
        for (int nt = 0; nt < 4; ++nt) {
            const int ncol = nbase + nt * 16 + n;
            const float bv = b0[ncol];
            #pragma unroll
            for (int r = 0; r < 4; ++r) {
                int mrow = mbase + mt * 16 + quad * 4 + r;
                if (mrow < M_N)
                    outp[(size_t)mrow * D_N + ncol] = acc[mt][nt][r] + bv;
            }
        }
}

// MFMA flash attention v2 (R3-verified, 113 us): 32 q-rows per wave,
// no-max softmax, row-sum via ones-column MFMA, ping-pong P LDS,
// XCD-swizzled grid (1280 blocks = 5/CU).
__global__ __launch_bounds__(256) void fattn_kernel(
    const unsigned short* __restrict__ qb,
    const unsigned short* __restrict__ kb,
    const unsigned short* __restrict__ vt,
    unsigned short* __restrict__ attn)
{
    __shared__ __align__(16) unsigned short Plds[4][2][2][16 * 32]; // wave/pp/chain

    const int tid = threadIdx.x;
    const int wave = tid >> 6, lane = tid & 63;
    const int quad = lane >> 4, n = lane & 15;

    const int bid = blockIdx.x;
    const int xcd = bid & 7, t = bid >> 3;      // t: 0..159
    const int qt = t % 5, hl = t / 5;           // hl: 0..31
    const int bh = hl * 8 + xcd;
    const int q0 = qt * 128 + wave * 32;        // 32 rows per wave

    const bf16x8 zf{};
    const unsigned short* qrow0 = qb + ((size_t)bh * S_N + q0 + n) * HD_N;
    const unsigned short* qrow1 = qrow0 + 16 * HD_N;
    bf16x8 aq00 = *(const bf16x8*)(qrow0 + quad * 8);
    bf16x8 aq01 = *(const bf16x8*)(qrow0 + 32 + quad * 8);
    bf16x8 aq02 = (quad < 2) ? *(const bf16x8*)(qrow0 + 64 + quad * 8) : zf;
    bf16x8 aq10 = *(const bf16x8*)(qrow1 + quad * 8);
    bf16x8 aq11 = *(const bf16x8*)(qrow1 + 32 + quad * 8);
    bf16x8 aq12 = (quad < 2) ? *(const bf16x8*)(qrow1 + 64 + quad * 8) : zf;

    // ones B-fragment: column 0 = 1 -> o[5][r] = sum_k P[r][k]
    const bf16_t one = (bf16_t)1.0f;
    const bf16x8 vones_all = {one, one, one, one, one, one, one, one};
    const bf16x8 vones = (n == 0) ? vones_all : zf;

    f32x4 o0[6] = {};
    f32x4 o1[6] = {};

    const unsigned short* kbase = kb + (size_t)bh * S_N * HD_N;
    const unsigned short* vbase = vt + (size_t)bh * HD_N * VT_S;

    #pragma unroll 2
    for (int t0 = 0; t0 < 608; t0 += 32) {
        const int pp = (t0 >> 5) & 1;
        unsigned short* pl0 = &Plds[wave][pp][0][0];
        unsigned short* pl1 = &Plds[wave][pp][1][0];

        // ---- shared K fragments for this 32-key slab ----
        const unsigned short* krA = kbase + (size_t)(t0 + n) * HD_N;
        const unsigned short* krB = krA + 16 * HD_N;
        bf16x8 bA0 = *(const bf16x8*)(krA + quad * 8);
        bf16x8 bA1 = *(const bf16x8*)(krA + 32 + quad * 8);
        bf16x8 bA2 = (quad < 2) ? *(const bf16x8*)(krA + 64 + quad * 8) : zf;
        bf16x8 bB0 = *(const bf16x8*)(krB + quad * 8);
        bf16x8 bB1 = *(const bf16x8*)(krB + 32 + quad * 8);
        bf16x8 bB2 = (quad < 2) ? *(const bf16x8*)(krB + 64 + quad * 8) : zf;

        // ---- QK^T both chains ----
        f32x4 c00{}, c01{}, c10{}, c11{};
        c00 = __builtin_amdgcn_mfma_f32_16x16x32_bf16(aq00, bA0, c00, 0, 0, 0);
        c00 = __builtin_amdgcn_mfma_f32_16x16x32_bf16(aq01, bA1, c00, 0, 0, 0);
        c00 = __builtin_amdgcn_mfma_f32_16x16x32_bf16(aq02, bA2, c00, 0, 0, 0);
        c01 = __builtin_amdgcn_mfma_f32_16x16x32_bf16(aq00, bB0, c01, 0, 0, 0);
        c01 = __builtin_amdgcn_mfma_f32_16x16x32_bf16(aq01, bB1, c01, 0, 0, 0);
        c01 = __builtin_amdgcn_mfma_f32_16x16x32_bf16(aq02, bB2, c01, 0, 0, 0);
        c10 = __builtin_amdgcn_mfma_f32_16x16x32_bf16(aq10, bA0, c10, 0, 0, 0);
        c10 = __builtin_amdgcn_mfma_f32_16x16x32_bf16(aq11, bA1, c10, 0, 0, 0);
        c10 = __builtin_amdgcn_mfma_f32_16x16x32_bf16(aq12, bA2, c10, 0, 0, 0);
        c11 = __builtin_amdgcn_mfma_f32_16x16x32_bf16(aq10, bB0, c11, 0, 0, 0);
        c11 = __builtin_amdgcn_mfma_f32_16x16x32_bf16(aq11, bB1, c11, 0, 0, 0);
        c11 = __builtin_amdgcn_mfma_f32_16x16x32_bf16(aq12, bB2, c11, 0, 0, 0);

        const bool mA = (t0 + n) >= S_N;
        const bool mB = (t0 + 16 + n) >= S_N;

        #pragma unroll
        for (int r = 0; r < 4; ++r) {
            float p00 = mA ? 0.0f : __expf(c00[r]);
            float p01 = mB ? 0.0f : __expf(c01[r]);
            float p10 = mA ? 0.0f : __expf(c10[r]);
            float p11 = mB ? 0.0f : __expf(c11[r]);
            pl0[(quad * 4 + r) * 32 + n]      = f2bf(p00);
            pl0[(quad * 4 + r) * 32 + 16 + n] = f2bf(p01);
            pl1[(quad * 4 + r) * 32 + n]      = f2bf(p10);
            pl1[(quad * 4 + r) * 32 + 16 + n] = f2bf(p11);
        }

        bf16x8 ap0 = *(const bf16x8*)(pl0 + n * 32 + quad * 8);
        bf16x8 ap1 = *(const bf16x8*)(pl1 + n * 32 + quad * 8);

        #pragma unroll
        for (int nt = 0; nt < 5; ++nt) {
            const unsigned short* vr = vbase + (size_t)(nt * 16 + n) * VT_S + t0 + quad * 8;
            bf16x8 bv = *(const bf16x8*)vr;
            o0[nt] = __builtin_amdgcn_mfma_f32_16x16x32_bf16(ap0, bv, o0[nt], 0, 0, 0);
            o1[nt] = __builtin_amdgcn_mfma_f32_16x16x32_bf16(ap1, bv, o1[nt], 0, 0, 0);
        }
        o0[5] = __builtin_amdgcn_mfma_f32_16x16x32_bf16(ap0, vones, o0[5], 0, 0, 0);
        o1[5] = __builtin_amdgcn_mfma_f32_16x16x32_bf16(ap1, vones, o1[5], 0, 0, 0);
    }

    const int b = bh >> 4, h = bh & 15;
    #pragma unroll
    for (int r = 0; r < 4; ++r) {
        float l0 = __shfl(o0[5][r], lane & 48);   // col-0 lane of this quad
        float l1 = __shfl(o1[5][r], lane & 48);
        float linv0 = 1.0f / l0, linv1 = 1.0f / l1;
        int s0 = q0 + quad * 4 + r;
        int s1 = s0 + 16;
        #pragma unroll
        for (int nt = 0; nt < 5; ++nt) {
            if (s0 < S_N)
                attn[((size_t)b * S_N + s0) * D_N + h * HD_N + nt * 16 + n] =
                    f2bf(o0[nt][r] * linv0);
            if (s1 < S_N)
                attn[((size_t)b * S_N + s1) * D_N + h * HD_N + nt * 16 + n] =
                    f2bf(o1[nt][r] * linv1);
        }
    }
}

extern "C" void kernel_launch(void* const* d_in, const int* in_sizes, int n_in,
                              void* d_out, int out_size, void* d_ws, size_t ws_size,
                              hipStream_t stream) {
    const float* hs = (const float*)d_in[0];
    const float* fc = (const float*)d_in[1];
    const float* fs = (const float*)d_in[2];
    const float* Wq = (const float*)d_in[3];
    const float* bq = (const float*)d_in[4];
    const float* Wk = (const float*)d_in[5];
    const float* bk = (const float*)d_in[6];
    const float* Wv = (const float*)d_in[7];
    const float* bv = (const float*)d_in[8];
    const float* Wo = (const float*)d_in[9];
    const float* bo = (const float*)d_in[10];
    float* out = (float*)d_out;

    char* ws = (char*)d_ws;
    size_t off = 0;
    auto alloc = [&](size_t bytes) {
        char* p = ws + off; off += (bytes + 255) & ~(size_t)255; return p;
    };
    unsigned short* hsb  = (unsigned short*)alloc((size_t)M_PAD2 * K_N * 2); // aliased as 'at'
    unsigned short* qb   = (unsigned short*)alloc((size_t)M_N * K_N * 2 + 32768);
    unsigned short* kb   = (unsigned short*)alloc((size_t)M_N * K_N * 2 + 32768);
    unsigned short* vt   = (unsigned short*)alloc((size_t)B_N * H_N * HD_N * VT_S * 2);
    unsigned short* Wall = (unsigned short*)alloc((size_t)4 * D_N * K_N * 2);

    const int HS4 = M_N * K_N / 4;   // 2,954,240
    dim3 blk(256);

    cvt_kernel<<<(HS4 + 255) / 256, blk, 0, stream>>>(hs, hsb, HS4);
    cvt4_kernel<<<(4 * W4_N + 255) / 256, blk, 0, stream>>>(Wq, Wk, Wv, Wo, Wall);

    // fused QKV: 256x256 8-phase, N = 3840 over [Wq;Wk;Wv], grid 15 x 37
    (void)hipFuncSetAttribute(reinterpret_cast<const void*>(&mgemm256_kernel),
                              hipFuncAttributeMaxDynamicSharedMemorySize, 131072);
    mgemm256_kernel<<<dim3(15, 37), dim3(512), 131072, stream>>>(
        hsb, Wall, bq, bk, bv, fc, fs, qb, kb, vt);

    fattn_kernel<<<dim3(1280), blk, 0, stream>>>(qb, kb, vt, hsb /*= at*/);

    mgemm64_kernel<<<dim3(10, 73), blk, 0, stream>>>(
        hsb, Wall + 3 * (size_t)D_N * K_N, bo, out);
}

// Round 9
// 419.235 us; speedup vs baseline: 1.1442x; 1.0863x over previous
//
#include <hip/hip_runtime.h>

#define B_N 16
#define S_N 577
#define D_N 1280
#define H_N 16
#define HD_N 80
#define HALF_N 40
#define M_N 9232
#define M_PAD 9344
#define K_N 1280
#define VT_S 608
#define QSCALE 0.11180339887498949f /* 1/sqrt(80) */

typedef __bf16 bf16_t;
typedef bf16_t bf16x8 __attribute__((ext_vector_type(8)));
typedef float f32x4 __attribute__((ext_vector_type(4)));

__device__ __forceinline__ float bf2f(unsigned short u) {
    union { unsigned int i; float f; } x; x.i = ((unsigned int)u) << 16; return x.f;
}
__device__ __forceinline__ unsigned short f2bf(float f) {
    union { unsigned int i; float f; } x; x.f = f;
    unsigned int r = x.i + 0x7FFFu + ((x.i >> 16) & 1u);
    return (unsigned short)(r >> 16);
}

__device__ __forceinline__ void gld_lds16(const unsigned short* g, unsigned short* l) {
    __builtin_amdgcn_global_load_lds(
        (const __attribute__((address_space(1))) unsigned int*)g,
        (__attribute__((address_space(3))) unsigned int*)l,
        16, 0, 0);
}

// fp32 -> bf16 (RNE), vectorized x4
__global__ __launch_bounds__(256) void cvt_kernel(const float* __restrict__ in,
                                                  unsigned short* __restrict__ out, int n4) {
    int i = blockIdx.x * 256 + threadIdx.x;
    if (i < n4) {
        float4 v = ((const float4*)in)[i];
        ushort4 o;
        o.x = f2bf(v.x); o.y = f2bf(v.y); o.z = f2bf(v.z); o.w = f2bf(v.w);
        ((ushort4*)out)[i] = o;
    }
}

// All 4 weight matrices -> one concatenated bf16 buffer [Wq;Wk;Wv;Wo]
#define W4_N (D_N * K_N / 4) /* 409600 float4 per W */
__global__ __launch_bounds__(256) void cvt4_kernel(
    const float* __restrict__ w0, const float* __restrict__ w1,
    const float* __restrict__ w2, const float* __restrict__ w3,
    unsigned short* __restrict__ out) {
    int i = blockIdx.x * 256 + threadIdx.x;
    if (i >= 4 * W4_N) return;
    int r = i / W4_N, j = i - r * W4_N;
    const float* src = (r == 0) ? w0 : (r == 1) ? w1 : (r == 2) ? w2 : w3;
    float4 v = ((const float4*)src)[j];
    ushort4 o;
    o.x = f2bf(v.x); o.y = f2bf(v.y); o.z = f2bf(v.z); o.w = f2bf(v.w);
    ((ushort4*)out)[i] = o;
}

// ---------------------------------------------------------------------------
// Fused-QKV GEMM, 128x128 tile, BK=64, 2-set dbuf + counted vmcnt — the
// R3-proven schedule — but with 8 WAVES (512 thr) instead of 4:
// per-wave output 64x32 -> acc[4][2] = 32 AGPR (vs 64), fragments 24 VGPR.
// Total regs/wave ~110-120 -> 4 waves/SIMD (vs 2 in ALL prior GEMMs, which
// is why R3/R7/R8 all stalled at ~205 us with MfmaUtil 19%).
// LDS 64 KiB (2 blocks/CU -> 16 waves/CU). Swizzle: phys 16B-blk =
// logical ^ (row&7) (R3 hardware-verified, 0 conflicts).
// Waves: wm = wave>>2 (M halves), wn = wave&3 (N quarters).
// grid 30x73, wsel = bx/10 selects q/k/v epilogue.
// ---------------------------------------------------------------------------
__global__ __launch_bounds__(512) void qkv8w_kernel(
    const unsigned short* __restrict__ A,
    const unsigned short* __restrict__ Wb,
    const float* __restrict__ b0, const float* __restrict__ b1,
    const float* __restrict__ b2,
    const float* __restrict__ cosb, const float* __restrict__ sinb,
    void* __restrict__ o0, void* __restrict__ o1, void* __restrict__ o2)
{
    __shared__ __align__(16) unsigned short As[2][128 * 64];  // 16 KiB each
    __shared__ __align__(16) unsigned short Bs[2][128 * 64];

    const int tid = threadIdx.x;
    const int wave = tid >> 6, lane = tid & 63;
    const int quad = lane >> 4, n = lane & 15;
    const int wm = wave >> 2, wn = wave & 3;
    const int m0 = blockIdx.y * 128, n0g = blockIdx.x * 128;

    // staging (512 thr): pass covers 64 rows x 64 cols (8 KiB).
    // thread -> row tid>>3 (0..63), phys blk tid&7; source col-blk
    // pre-swizzled cb = (tid&7) ^ ((tid>>3)&7)  [f(r)=r&7, R3-verified].
    // Second pass = +64 rows: (r+64)&7 == r&7, same swizzle.
    const int srow = tid >> 3;
    const int scb  = (tid & 7) ^ (srow & 7);

    const unsigned short* gA = A + (size_t)(m0 + srow) * K_N + scb * 8;
    const unsigned short* gB = Wb + (size_t)(n0g + srow) * K_N + scb * 8;
    // LDS dest: row*64 + (tid&7)*8 ushorts = tid*8 -> wave-uniform base
    // wave*512 + lane*8 (16B per lane, linear) ✓ gld_lds constraint.
    const int lofs = wave * 512;

    f32x4 acc[4][2] = {};

    auto stage = [&](int s, int kt) {
        const unsigned short* a = gA + kt * 64;
        const unsigned short* b = gB + kt * 64;
        gld_lds16(a, &As[s][lofs]);
        gld_lds16(a + (size_t)64 * K_N, &As[s][lofs + 4096]);
        gld_lds16(b, &Bs[s][lofs]);
        gld_lds16(b + (size_t)64 * K_N, &Bs[s][lofs + 4096]);
    };

    auto compute = [&](int s) {
        #pragma unroll
        for (int kk = 0; kk < 2; ++kk) {
            // logical k-blk (kk*4+quad) stored at ^(row&7); row&7 == n&7
            // (row bases wm*64, wn*32, mf*16, nf*16 are multiples of 16... 8).
            const int sa = ((((kk << 2) | quad) ^ (n & 7)) * 8);
            bf16x8 af[4], bfr[2];
            #pragma unroll
            for (int nf = 0; nf < 2; ++nf)
                bfr[nf] = *(const bf16x8*)&Bs[s][(wn * 32 + nf * 16 + n) * 64 + sa];
            #pragma unroll
            for (int mf = 0; mf < 4; ++mf)
                af[mf] = *(const bf16x8*)&As[s][(wm * 64 + mf * 16 + n) * 64 + sa];
            #pragma unroll
            for (int mf = 0; mf < 4; ++mf)
                #pragma unroll
                for (int nf = 0; nf < 2; ++nf)
                    acc[mf][nf] = __builtin_amdgcn_mfma_f32_16x16x32_bf16(
                        af[mf], bfr[nf], acc[mf][nf], 0, 0, 0);
        }
    };

    // prologue: tile 0's 4 loads in flight (not drained here)
    stage(0, 0);

    // 20 K-tiles; compute 0..18 in-loop, 19 in epilogue (R3 schedule).
    #pragma unroll 2
    for (int t = 0; t < 19; ++t) {
        const int s = t & 1;
        stage(s ^ 1, t + 1);                       // 4 loads for tile t+1
        asm volatile("s_waitcnt vmcnt(4)" ::: "memory");  // tile t landed
        __builtin_amdgcn_s_barrier();              // publish tile t
        compute(s);                                // t+1 loads still flying
        __builtin_amdgcn_s_barrier();              // reads done -> set reusable
    }
    asm volatile("s_waitcnt vmcnt(0)" ::: "memory");
    __builtin_amdgcn_s_barrier();
    compute(1);                                    // tile 19

    // ---- fused QKV epilogue: wsel = bx/10 ----
    const int wsel = blockIdx.x / 10;   // block-uniform: 0=q, 1=k, 2=v
    const float* bias = (wsel == 0) ? b0 : (wsel == 1) ? b1 : b2;
    unsigned short* out =
        (unsigned short*)((wsel == 0) ? o0 : (wsel == 1) ? o1 : o2);
    const int nloc = n0g - wsel * 1280 + wn * 32;
    const int mbase = m0 + wm * 64;
    const bool evn = (n & 1) == 0;

    #pragma unroll
    for (int nf = 0; nf < 2; ++nf) {
        const int ncol = nloc + nf * 16 + n;
        const int h = ncol / HD_N, hd = ncol - h * HD_N;
        const float bv = bias[ncol];
        #pragma unroll
        for (int mf = 0; mf < 4; ++mf)
            #pragma unroll
            for (int r = 0; r < 4; ++r) {
                int mrow = mbase + mf * 16 + quad * 4 + r;
                int b = mrow / S_N, s = mrow - b * S_N;
                float v = acc[mf][nf][r] + bv;
                if (wsel == 2) {
                    if (mrow < M_N)
                        out[((size_t)(b * H_N + h) * HD_N + hd) * VT_S + s] = f2bf(v);
                } else {
                    float pv = __shfl_xor(v, 1);  // paired column (ncol^1)
                    float c  = cosb[s * HALF_N + (hd >> 1)];
                    float sn = sinb[s * HALF_N + (hd >> 1)];
                    float res = evn ? (v * c - pv * sn) : (pv * sn + v * c);
                    if (wsel == 0) res *= QSCALE;
                    if (mrow < M_N)
                        out[((size_t)(b * H_N + h) * S_N + s) * HD_N + hd] = f2bf(res);
                }
            }
    }
}

// MFMA GEMM, BK=64, XOR-swizzled LDS, double-buffer with counted vmcnt
// (R3-verified). Out-projection: fp32 (B,S,D) output (grid 10x73).
__global__ __launch_bounds__(256) void mgemm64_kernel(
    const unsigned short* __restrict__ A,
    const unsigned short* __restrict__ Wb,
    const float* __restrict__ b0,
    void* __restrict__ o0)
{
    __shared__ __align__(16) unsigned short As[2][128 * 64];
    __shared__ __align__(16) unsigned short Bs[2][128 * 64];

    const int tid = threadIdx.x;
    const int wave = tid >> 6, lane = tid & 63;
    const int quad = lane >> 4, n = lane & 15;
    const int wm = wave >> 1, wn = wave & 1;
    const int m0 = blockIdx.y * 128, n0g = blockIdx.x * 128;

    const int srow = lane >> 3;
    const int scol = (((lane & 7) ^ srow) * 8);

    const unsigned short* gA = A + (size_t)(m0 + wave * 32 + srow) * K_N + scol;
    const unsigned short* gB = Wb + (size_t)(n0g + wave * 32 + srow) * K_N + scol;
    const int lofs = wave * 32 * 64;

    f32x4 acc[4][4] = {};

    auto stage = [&](int pp, int k0) {
        unsigned short* lA = &As[pp][lofs];
        unsigned short* lB = &Bs[pp][lofs];
        #pragma unroll
        for (int i = 0; i < 4; ++i) {
            gld_lds16(gA + k0 + i * 8 * K_N, lA + i * 512);
            gld_lds16(gB + k0 + i * 8 * K_N, lB + i * 512);
        }
    };

    auto compute = [&](int pp) {
        #pragma unroll
        for (int kk = 0; kk < 2; ++kk) {
            const int sa = ((((kk << 2) | quad) ^ (n & 7)) * 8);
            bf16x8 af[4], bfr[4];
            #pragma unroll
            for (int mt = 0; mt < 4; ++mt)
                af[mt] = *(const bf16x8*)&As[pp][(wm * 64 + mt * 16 + n) * 64 + sa];
            #pragma unroll
            for (int nt = 0; nt < 4; ++nt)
                bfr[nt] = *(const bf16x8*)&Bs[pp][(wn * 64 + nt * 16 + n) * 64 + sa];
            #pragma unroll
            for (int mt = 0; mt < 4; ++mt)
                #pragma unroll
                for (int nt = 0; nt < 4; ++nt)
                    acc[mt][nt] = __builtin_amdgcn_mfma_f32_16x16x32_bf16(
                        af[mt], bfr[nt], acc[mt][nt], 0, 0, 0);
        }
    };

    stage(0, 0);

    #pragma unroll 2
    for (int t = 0; t < 19; ++t) {
        const int pp = t & 1;
        stage(pp ^ 1, (t + 1) * 64);
        asm volatile("s_waitcnt vmcnt(8)" ::: "memory");
        __builtin_amdgcn_s_barrier();
        compute(pp);
        __builtin_amdgcn_s_barrier();
    }
    asm volatile("s_waitcnt vmcnt(0)" ::: "memory");
    __builtin_amdgcn_s_barrier();
    compute(1);

    const int mbase = m0 + wm * 64;
    const int nbase = n0g + wn * 64;
    float* outp = (float*)o0;
    #pragma unroll
    for (int mt = 0; mt < 4; ++mt)
        #pragma unroll
        for (int nt = 0; nt < 4; ++nt) {
            const int ncol = nbase + nt * 16 + n;
            const float bv = b0[ncol];
            #pragma unroll
            for (int r = 0; r < 4; ++r) {
                int mrow = mbase + mt * 16 + quad * 4 + r;
                if (mrow < M_N)
                    outp[(size_t)mrow * D_N + ncol] = acc[mt][nt][r] + bv;
            }
        }
}

// MFMA flash attention v2 (R3-verified, 113 us): 32 q-rows per wave,
// no-max softmax, row-sum via ones-column MFMA, ping-pong P LDS,
// XCD-swizzled grid (1280 blocks = 5/CU).
__global__ __launch_bounds__(256) void fattn_kernel(
    const unsigned short* __restrict__ qb,
    const unsigned short* __restrict__ kb,
    const unsigned short* __restrict__ vt,
    unsigned short* __restrict__ attn)
{
    __shared__ __align__(16) unsigned short Plds[4][2][2][16 * 32]; // wave/pp/chain

    const int tid = threadIdx.x;
    const int wave = tid >> 6, lane = tid & 63;
    const int quad = lane >> 4, n = lane & 15;

    const int bid = blockIdx.x;
    const int xcd = bid & 7, t = bid >> 3;      // t: 0..159
    const int qt = t % 5, hl = t / 5;           // hl: 0..31
    const int bh = hl * 8 + xcd;
    const int q0 = qt * 128 + wave * 32;        // 32 rows per wave

    const bf16x8 zf{};
    const unsigned short* qrow0 = qb + ((size_t)bh * S_N + q0 + n) * HD_N;
    const unsigned short* qrow1 = qrow0 + 16 * HD_N;
    bf16x8 aq00 = *(const bf16x8*)(qrow0 + quad * 8);
    bf16x8 aq01 = *(const bf16x8*)(qrow0 + 32 + quad * 8);
    bf16x8 aq02 = (quad < 2) ? *(const bf16x8*)(qrow0 + 64 + quad * 8) : zf;
    bf16x8 aq10 = *(const bf16x8*)(qrow1 + quad * 8);
    bf16x8 aq11 = *(const bf16x8*)(qrow1 + 32 + quad * 8);
    bf16x8 aq12 = (quad < 2) ? *(const bf16x8*)(qrow1 + 64 + quad * 8) : zf;

    // ones B-fragment: column 0 = 1 -> o[5][r] = sum_k P[r][k]
    const bf16_t one = (bf16_t)1.0f;
    const bf16x8 vones_all = {one, one, one, one, one, one, one, one};
    const bf16x8 vones = (n == 0) ? vones_all : zf;

    f32x4 o0[6] = {};
    f32x4 o1[6] = {};

    const unsigned short* kbase = kb + (size_t)bh * S_N * HD_N;
    const unsigned short* vbase = vt + (size_t)bh * HD_N * VT_S;

    #pragma unroll 2
    for (int t0 = 0; t0 < 608; t0 += 32) {
        const int pp = (t0 >> 5) & 1;
        unsigned short* pl0 = &Plds[wave][pp][0][0];
        unsigned short* pl1 = &Plds[wave][pp][1][0];

        // ---- shared K fragments for this 32-key slab ----
        const unsigned short* krA = kbase + (size_t)(t0 + n) * HD_N;
        const unsigned short* krB = krA + 16 * HD_N;
        bf16x8 bA0 = *(const bf16x8*)(krA + quad * 8);
        bf16x8 bA1 = *(const bf16x8*)(krA + 32 + quad * 8);
        bf16x8 bA2 = (quad < 2) ? *(const bf16x8*)(krA + 64 + quad * 8) : zf;
        bf16x8 bB0 = *(const bf16x8*)(krB + quad * 8);
        bf16x8 bB1 = *(const bf16x8*)(krB + 32 + quad * 8);
        bf16x8 bB2 = (quad < 2) ? *(const bf16x8*)(krB + 64 + quad * 8) : zf;

        // ---- QK^T both chains ----
        f32x4 c00{}, c01{}, c10{}, c11{};
        c00 = __builtin_amdgcn_mfma_f32_16x16x32_bf16(aq00, bA0, c00, 0, 0, 0);
        c00 = __builtin_amdgcn_mfma_f32_16x16x32_bf16(aq01, bA1, c00, 0, 0, 0);
        c00 = __builtin_amdgcn_mfma_f32_16x16x32_bf16(aq02, bA2, c00, 0, 0, 0);
        c01 = __builtin_amdgcn_mfma_f32_16x16x32_bf16(aq00, bB0, c01, 0, 0, 0);
        c01 = __builtin_amdgcn_mfma_f32_16x16x32_bf16(aq01, bB1, c01, 0, 0, 0);
        c01 = __builtin_amdgcn_mfma_f32_16x16x32_bf16(aq02, bB2, c01, 0, 0, 0);
        c10 = __builtin_amdgcn_mfma_f32_16x16x32_bf16(aq10, bA0, c10, 0, 0, 0);
        c10 = __builtin_amdgcn_mfma_f32_16x16x32_bf16(aq11, bA1, c10, 0, 0, 0);
        c10 = __builtin_amdgcn_mfma_f32_16x16x32_bf16(aq12, bA2, c10, 0, 0, 0);
        c11 = __builtin_amdgcn_mfma_f32_16x16x32_bf16(aq10, bB0, c11, 0, 0, 0);
        c11 = __builtin_amdgcn_mfma_f32_16x16x32_bf16(aq11, bB1, c11, 0, 0, 0);
        c11 = __builtin_amdgcn_mfma_f32_16x16x32_bf16(aq12, bB2, c11, 0, 0, 0);

        const bool mA = (t0 + n) >= S_N;
        const bool mB = (t0 + 16 + n) >= S_N;

        #pragma unroll
        for (int r = 0; r < 4; ++r) {
            float p00 = mA ? 0.0f : __expf(c00[r]);
            float p01 = mB ? 0.0f : __expf(c01[r]);
            float p10 = mA ? 0.0f : __expf(c10[r]);
            float p11 = mB ? 0.0f : __expf(c11[r]);
            pl0[(quad * 4 + r) * 32 + n]      = f2bf(p00);
            pl0[(quad * 4 + r) * 32 + 16 + n] = f2bf(p01);
            pl1[(quad * 4 + r) * 32 + n]      = f2bf(p10);
            pl1[(quad * 4 + r) * 32 + 16 + n] = f2bf(p11);
        }

        bf16x8 ap0 = *(const bf16x8*)(pl0 + n * 32 + quad * 8);
        bf16x8 ap1 = *(const bf16x8*)(pl1 + n * 32 + quad * 8);

        #pragma unroll
        for (int nt = 0; nt < 5; ++nt) {
            const unsigned short* vr = vbase + (size_t)(nt * 16 + n) * VT_S + t0 + quad * 8;
            bf16x8 bv = *(const bf16x8*)vr;
            o0[nt] = __builtin_amdgcn_mfma_f32_16x16x32_bf16(ap0, bv, o0[nt], 0, 0, 0);
            o1[nt] = __builtin_amdgcn_mfma_f32_16x16x32_bf16(ap1, bv, o1[nt], 0, 0, 0);
        }
        o0[5] = __builtin_amdgcn_mfma_f32_16x16x32_bf16(ap0, vones, o0[5], 0, 0, 0);
        o1[5] = __builtin_amdgcn_mfma_f32_16x16x32_bf16(ap1, vones, o1[5], 0, 0, 0);
    }

    const int b = bh >> 4, h = bh & 15;
    #pragma unroll
    for (int r = 0; r < 4; ++r) {
        float l0 = __shfl(o0[5][r], lane & 48);   // col-0 lane of this quad
        float l1 = __shfl(o1[5][r], lane & 48);
        float linv0 = 1.0f / l0, linv1 = 1.0f / l1;
        int s0 = q0 + quad * 4 + r;
        int s1 = s0 + 16;
        #pragma unroll
        for (int nt = 0; nt < 5; ++nt) {
            if (s0 < S_N)
                attn[((size_t)b * S_N + s0) * D_N + h * HD_N + nt * 16 + n] =
                    f2bf(o0[nt][r] * linv0);
            if (s1 < S_N)
                attn[((size_t)b * S_N + s1) * D_N + h * HD_N + nt * 16 + n] =
                    f2bf(o1[nt][r] * linv1);
        }
    }
}

extern "C" void kernel_launch(void* const* d_in, const int* in_sizes, int n_in,
                              void* d_out, int out_size, void* d_ws, size_t ws_size,
                              hipStream_t stream) {
    const float* hs = (const float*)d_in[0];
    const float* fc = (const float*)d_in[1];
    const float* fs = (const float*)d_in[2];
    const float* Wq = (const float*)d_in[3];
    const float* bq = (const float*)d_in[4];
    const float* Wk = (const float*)d_in[5];
    const float* bk = (const float*)d_in[6];
    const float* Wv = (const float*)d_in[7];
    const float* bv = (const float*)d_in[8];
    const float* Wo = (const float*)d_in[9];
    const float* bo = (const float*)d_in[10];
    float* out = (float*)d_out;

    char* ws = (char*)d_ws;
    size_t off = 0;
    auto alloc = [&](size_t bytes) {
        char* p = ws + off; off += (bytes + 255) & ~(size_t)255; return p;
    };
    unsigned short* hsb  = (unsigned short*)alloc((size_t)M_PAD * K_N * 2); // aliased as 'at'
    unsigned short* qb   = (unsigned short*)alloc((size_t)M_N * K_N * 2 + 32768);
    unsigned short* kb   = (unsigned short*)alloc((size_t)M_N * K_N * 2 + 32768);
    unsigned short* vt   = (unsigned short*)alloc((size_t)B_N * H_N * HD_N * VT_S * 2);
    unsigned short* Wall = (unsigned short*)alloc((size_t)4 * D_N * K_N * 2);

    const int HS4 = M_N * K_N / 4;   // 2,954,240
    dim3 blk(256);

    cvt_kernel<<<(HS4 + 255) / 256, blk, 0, stream>>>(hs, hsb, HS4);
    cvt4_kernel<<<(4 * W4_N + 255) / 256, blk, 0, stream>>>(Wq, Wk, Wv, Wo, Wall);

    // fused QKV: 8-wave 128x128 (4 waves/SIMD), N = 3840 over [Wq;Wk;Wv]
    qkv8w_kernel<<<dim3(30, 73), dim3(512), 0, stream>>>(
        hsb, Wall, bq, bk, bv, fc, fs, qb, kb, vt);

    fattn_kernel<<<dim3(1280), blk, 0, stream>>>(qb, kb, vt, hsb /*= at*/);

    mgemm64_kernel<<<dim3(10, 73), blk, 0, stream>>>(
        hsb, Wall + 3 * (size_t)D_N * K_N, bo, out);
}

// Round 10
// 416.323 us; speedup vs baseline: 1.1522x; 1.0070x over previous
//
#include <hip/hip_runtime.h>

#define B_N 16
#define S_N 577
#define D_N 1280
#define H_N 16
#define HD_N 80
#define HALF_N 40
#define M_N 9232
#define M_PAD 9344
#define K_N 1280
#define VT_S 608
#define QSCALE 0.11180339887498949f /* 1/sqrt(80) */

typedef __bf16 bf16_t;
typedef bf16_t bf16x8 __attribute__((ext_vector_type(8)));
typedef float f32x4 __attribute__((ext_vector_type(4)));

__device__ __forceinline__ float bf2f(unsigned short u) {
    union { unsigned int i; float f; } x; x.i = ((unsigned int)u) << 16; return x.f;
}
__device__ __forceinline__ unsigned short f2bf(float f) {
    union { unsigned int i; float f; } x; x.f = f;
    unsigned int r = x.i + 0x7FFFu + ((x.i >> 16) & 1u);
    return (unsigned short)(r >> 16);
}

__device__ __forceinline__ void gld_lds16(const unsigned short* g, unsigned short* l) {
    __builtin_amdgcn_global_load_lds(
        (const __attribute__((address_space(1))) unsigned int*)g,
        (__attribute__((address_space(3))) unsigned int*)l,
        16, 0, 0);
}

// fp32 -> bf16 (RNE), vectorized x4
__global__ __launch_bounds__(256) void cvt_kernel(const float* __restrict__ in,
                                                  unsigned short* __restrict__ out, int n4) {
    int i = blockIdx.x * 256 + threadIdx.x;
    if (i < n4) {
        float4 v = ((const float4*)in)[i];
        ushort4 o;
        o.x = f2bf(v.x); o.y = f2bf(v.y); o.z = f2bf(v.z); o.w = f2bf(v.w);
        ((ushort4*)out)[i] = o;
    }
}

// All 4 weight matrices -> one concatenated bf16 buffer [Wq;Wk;Wv;Wo]
#define W4_N (D_N * K_N / 4) /* 409600 float4 per W */
__global__ __launch_bounds__(256) void cvt4_kernel(
    const float* __restrict__ w0, const float* __restrict__ w1,
    const float* __restrict__ w2, const float* __restrict__ w3,
    unsigned short* __restrict__ out) {
    int i = blockIdx.x * 256 + threadIdx.x;
    if (i >= 4 * W4_N) return;
    int r = i / W4_N, j = i - r * W4_N;
    const float* src = (r == 0) ? w0 : (r == 1) ? w1 : (r == 2) ? w2 : w3;
    float4 v = ((const float4*)src)[j];
    ushort4 o;
    o.x = f2bf(v.x); o.y = f2bf(v.y); o.z = f2bf(v.z); o.w = f2bf(v.w);
    ((ushort4*)out)[i] = o;
}

// ---------------------------------------------------------------------------
// 8-wave 128x128 GEMM core (R9-proven: 4 waves/SIMD, VGPR 52, occ 37%,
// 0 bank conflicts): BK=64, 2-set dbuf, counted vmcnt(4).
// Per-wave output 64x32 -> acc[4][2] = 32 AGPR.
// Waves: wm = wave>>2 (M halves), wn = wave&3 (N quarters).
// MODE 4: fused QKV epilogue (grid 30x73, wsel = bx/10 -> q/k/v).
// MODE 3: out-projection, fp32 (B,S,D) output (grid 10x73).
// ---------------------------------------------------------------------------
template <int MODE>
__global__ __launch_bounds__(512) void gemm8w_kernel(
    const unsigned short* __restrict__ A,
    const unsigned short* __restrict__ Wb,
    const float* __restrict__ b0, const float* __restrict__ b1,
    const float* __restrict__ b2,
    const float* __restrict__ cosb, const float* __restrict__ sinb,
    void* __restrict__ o0, void* __restrict__ o1, void* __restrict__ o2)
{
    __shared__ __align__(16) unsigned short As[2][128 * 64];  // 16 KiB each
    __shared__ __align__(16) unsigned short Bs[2][128 * 64];

    const int tid = threadIdx.x;
    const int wave = tid >> 6, lane = tid & 63;
    const int quad = lane >> 4, n = lane & 15;
    const int wm = wave >> 2, wn = wave & 3;
    const int m0 = blockIdx.y * 128, n0g = blockIdx.x * 128;

    // staging (512 thr): pass covers 64 rows x 64 cols (8 KiB).
    // thread -> row tid>>3 (0..63), phys blk tid&7; source col-blk
    // pre-swizzled cb = (tid&7) ^ ((tid>>3)&7)  [f(r)=r&7, R3/R9-verified].
    const int srow = tid >> 3;
    const int scb  = (tid & 7) ^ (srow & 7);

    const unsigned short* gA = A + (size_t)(m0 + srow) * K_N + scb * 8;
    const unsigned short* gB = Wb + (size_t)(n0g + srow) * K_N + scb * 8;
    const int lofs = wave * 512;

    f32x4 acc[4][2] = {};

    auto stage = [&](int s, int kt) {
        const unsigned short* a = gA + kt * 64;
        const unsigned short* b = gB + kt * 64;
        gld_lds16(a, &As[s][lofs]);
        gld_lds16(a + (size_t)64 * K_N, &As[s][lofs + 4096]);
        gld_lds16(b, &Bs[s][lofs]);
        gld_lds16(b + (size_t)64 * K_N, &Bs[s][lofs + 4096]);
    };

    auto compute = [&](int s) {
        #pragma unroll
        for (int kk = 0; kk < 2; ++kk) {
            const int sa = ((((kk << 2) | quad) ^ (n & 7)) * 8);
            bf16x8 af[4], bfr[2];
            #pragma unroll
            for (int nf = 0; nf < 2; ++nf)
                bfr[nf] = *(const bf16x8*)&Bs[s][(wn * 32 + nf * 16 + n) * 64 + sa];
            #pragma unroll
            for (int mf = 0; mf < 4; ++mf)
                af[mf] = *(const bf16x8*)&As[s][(wm * 64 + mf * 16 + n) * 64 + sa];
            #pragma unroll
            for (int mf = 0; mf < 4; ++mf)
                #pragma unroll
                for (int nf = 0; nf < 2; ++nf)
                    acc[mf][nf] = __builtin_amdgcn_mfma_f32_16x16x32_bf16(
                        af[mf], bfr[nf], acc[mf][nf], 0, 0, 0);
        }
    };

    // prologue: tile 0's 4 loads in flight (not drained here)
    stage(0, 0);

    // 20 K-tiles; compute 0..18 in-loop, 19 in epilogue.
    #pragma unroll 2
    for (int t = 0; t < 19; ++t) {
        const int s = t & 1;
        stage(s ^ 1, t + 1);                       // 4 loads for tile t+1
        asm volatile("s_waitcnt vmcnt(4)" ::: "memory");  // tile t landed
        __builtin_amdgcn_s_barrier();              // publish tile t
        compute(s);                                // t+1 loads still flying
        __builtin_amdgcn_s_barrier();              // reads done -> set reusable
    }
    asm volatile("s_waitcnt vmcnt(0)" ::: "memory");
    __builtin_amdgcn_s_barrier();
    compute(1);                                    // tile 19

    const int mbase = m0 + wm * 64;

    if (MODE == 3) {
        const int nbase = n0g + wn * 32;
        float* outp = (float*)o0;
        #pragma unroll
        for (int nf = 0; nf < 2; ++nf) {
            const int ncol = nbase + nf * 16 + n;
            const float bv = b0[ncol];
            #pragma unroll
            for (int mf = 0; mf < 4; ++mf)
                #pragma unroll
                for (int r = 0; r < 4; ++r) {
                    int mrow = mbase + mf * 16 + quad * 4 + r;
                    if (mrow < M_N)
                        outp[(size_t)mrow * D_N + ncol] = acc[mf][nf][r] + bv;
                }
        }
    } else {
        const int wsel = blockIdx.x / 10;   // block-uniform: 0=q, 1=k, 2=v
        const float* bias = (wsel == 0) ? b0 : (wsel == 1) ? b1 : b2;
        unsigned short* out =
            (unsigned short*)((wsel == 0) ? o0 : (wsel == 1) ? o1 : o2);
        const int nloc = n0g - wsel * 1280 + wn * 32;
        const bool evn = (n & 1) == 0;

        #pragma unroll
        for (int nf = 0; nf < 2; ++nf) {
            const int ncol = nloc + nf * 16 + n;
            const int h = ncol / HD_N, hd = ncol - h * HD_N;
            const float bv = bias[ncol];
            #pragma unroll
            for (int mf = 0; mf < 4; ++mf)
                #pragma unroll
                for (int r = 0; r < 4; ++r) {
                    int mrow = mbase + mf * 16 + quad * 4 + r;
                    int b = mrow / S_N, s = mrow - b * S_N;
                    float v = acc[mf][nf][r] + bv;
                    if (wsel == 2) {
                        if (mrow < M_N)
                            out[((size_t)(b * H_N + h) * HD_N + hd) * VT_S + s] = f2bf(v);
                    } else {
                        float pv = __shfl_xor(v, 1);  // paired column (ncol^1)
                        float c  = cosb[s * HALF_N + (hd >> 1)];
                        float sn = sinb[s * HALF_N + (hd >> 1)];
                        float res = evn ? (v * c - pv * sn) : (pv * sn + v * c);
                        if (wsel == 0) res *= QSCALE;
                        if (mrow < M_N)
                            out[((size_t)(b * H_N + h) * S_N + s) * HD_N + hd] = f2bf(res);
                    }
                }
        }
    }
}

// MFMA flash attention v2 (R3-verified, 113 us): 32 q-rows per wave,
// no-max softmax, row-sum via ones-column MFMA, ping-pong P LDS,
// XCD-swizzled grid (1280 blocks = 5/CU).
__global__ __launch_bounds__(256) void fattn_kernel(
    const unsigned short* __restrict__ qb,
    const unsigned short* __restrict__ kb,
    const unsigned short* __restrict__ vt,
    unsigned short* __restrict__ attn)
{
    __shared__ __align__(16) unsigned short Plds[4][2][2][16 * 32]; // wave/pp/chain

    const int tid = threadIdx.x;
    const int wave = tid >> 6, lane = tid & 63;
    const int quad = lane >> 4, n = lane & 15;

    const int bid = blockIdx.x;
    const int xcd = bid & 7, t = bid >> 3;      // t: 0..159
    const int qt = t % 5, hl = t / 5;           // hl: 0..31
    const int bh = hl * 8 + xcd;
    const int q0 = qt * 128 + wave * 32;        // 32 rows per wave

    const bf16x8 zf{};
    const unsigned short* qrow0 = qb + ((size_t)bh * S_N + q0 + n) * HD_N;
    const unsigned short* qrow1 = qrow0 + 16 * HD_N;
    bf16x8 aq00 = *(const bf16x8*)(qrow0 + quad * 8);
    bf16x8 aq01 = *(const bf16x8*)(qrow0 + 32 + quad * 8);
    bf16x8 aq02 = (quad < 2) ? *(const bf16x8*)(qrow0 + 64 + quad * 8) : zf;
    bf16x8 aq10 = *(const bf16x8*)(qrow1 + quad * 8);
    bf16x8 aq11 = *(const bf16x8*)(qrow1 + 32 + quad * 8);
    bf16x8 aq12 = (quad < 2) ? *(const bf16x8*)(qrow1 + 64 + quad * 8) : zf;

    // ones B-fragment: column 0 = 1 -> o[5][r] = sum_k P[r][k]
    const bf16_t one = (bf16_t)1.0f;
    const bf16x8 vones_all = {one, one, one, one, one, one, one, one};
    const bf16x8 vones = (n == 0) ? vones_all : zf;

    f32x4 o0[6] = {};
    f32x4 o1[6] = {};

    const unsigned short* kbase = kb + (size_t)bh * S_N * HD_N;
    const unsigned short* vbase = vt + (size_t)bh * HD_N * VT_S;

    #pragma unroll 2
    for (int t0 = 0; t0 < 608; t0 += 32) {
        const int pp = (t0 >> 5) & 1;
        unsigned short* pl0 = &Plds[wave][pp][0][0];
        unsigned short* pl1 = &Plds[wave][pp][1][0];

        // ---- shared K fragments for this 32-key slab ----
        const unsigned short* krA = kbase + (size_t)(t0 + n) * HD_N;
        const unsigned short* krB = krA + 16 * HD_N;
        bf16x8 bA0 = *(const bf16x8*)(krA + quad * 8);
        bf16x8 bA1 = *(const bf16x8*)(krA + 32 + quad * 8);
        bf16x8 bA2 = (quad < 2) ? *(const bf16x8*)(krA + 64 + quad * 8) : zf;
        bf16x8 bB0 = *(const bf16x8*)(krB + quad * 8);
        bf16x8 bB1 = *(const bf16x8*)(krB + 32 + quad * 8);
        bf16x8 bB2 = (quad < 2) ? *(const bf16x8*)(krB + 64 + quad * 8) : zf;

        // ---- QK^T both chains ----
        f32x4 c00{}, c01{}, c10{}, c11{};
        c00 = __builtin_amdgcn_mfma_f32_16x16x32_bf16(aq00, bA0, c00, 0, 0, 0);
        c00 = __builtin_amdgcn_mfma_f32_16x16x32_bf16(aq01, bA1, c00, 0, 0, 0);
        c00 = __builtin_amdgcn_mfma_f32_16x16x32_bf16(aq02, bA2, c00, 0, 0, 0);
        c01 = __builtin_amdgcn_mfma_f32_16x16x32_bf16(aq00, bB0, c01, 0, 0, 0);
        c01 = __builtin_amdgcn_mfma_f32_16x16x32_bf16(aq01, bB1, c01, 0, 0, 0);
        c01 = __builtin_amdgcn_mfma_f32_16x16x32_bf16(aq02, bB2, c01, 0, 0, 0);
        c10 = __builtin_amdgcn_mfma_f32_16x16x32_bf16(aq10, bA0, c10, 0, 0, 0);
        c10 = __builtin_amdgcn_mfma_f32_16x16x32_bf16(aq11, bA1, c10, 0, 0, 0);
        c10 = __builtin_amdgcn_mfma_f32_16x16x32_bf16(aq12, bA2, c10, 0, 0, 0);
        c11 = __builtin_amdgcn_mfma_f32_16x16x32_bf16(aq10, bB0, c11, 0, 0, 0);
        c11 = __builtin_amdgcn_mfma_f32_16x16x32_bf16(aq11, bB1, c11, 0, 0, 0);
        c11 = __builtin_amdgcn_mfma_f32_16x16x32_bf16(aq12, bB2, c11, 0, 0, 0);

        const bool mA = (t0 + n) >= S_N;
        const bool mB = (t0 + 16 + n) >= S_N;

        #pragma unroll
        for (int r = 0; r < 4; ++r) {
            float p00 = mA ? 0.0f : __expf(c00[r]);
            float p01 = mB ? 0.0f : __expf(c01[r]);
            float p10 = mA ? 0.0f : __expf(c10[r]);
            float p11 = mB ? 0.0f : __expf(c11[r]);
            pl0[(quad * 4 + r) * 32 + n]      = f2bf(p00);
            pl0[(quad * 4 + r) * 32 + 16 + n] = f2bf(p01);
            pl1[(quad * 4 + r) * 32 + n]      = f2bf(p10);
            pl1[(quad * 4 + r) * 32 + 16 + n] = f2bf(p11);
        }

        bf16x8 ap0 = *(const bf16x8*)(pl0 + n * 32 + quad * 8);
        bf16x8 ap1 = *(const bf16x8*)(pl1 + n * 32 + quad * 8);

        #pragma unroll
        for (int nt = 0; nt < 5; ++nt) {
            const unsigned short* vr = vbase + (size_t)(nt * 16 + n) * VT_S + t0 + quad * 8;
            bf16x8 bv = *(const bf16x8*)vr;
            o0[nt] = __builtin_amdgcn_mfma_f32_16x16x32_bf16(ap0, bv, o0[nt], 0, 0, 0);
            o1[nt] = __builtin_amdgcn_mfma_f32_16x16x32_bf16(ap1, bv, o1[nt], 0, 0, 0);
        }
        o0[5] = __builtin_amdgcn_mfma_f32_16x16x32_bf16(ap0, vones, o0[5], 0, 0, 0);
        o1[5] = __builtin_amdgcn_mfma_f32_16x16x32_bf16(ap1, vones, o1[5], 0, 0, 0);
    }

    const int b = bh >> 4, h = bh & 15;
    #pragma unroll
    for (int r = 0; r < 4; ++r) {
        float l0 = __shfl(o0[5][r], lane & 48);   // col-0 lane of this quad
        float l1 = __shfl(o1[5][r], lane & 48);
        float linv0 = 1.0f / l0, linv1 = 1.0f / l1;
        int s0 = q0 + quad * 4 + r;
        int s1 = s0 + 16;
        #pragma unroll
        for (int nt = 0; nt < 5; ++nt) {
            if (s0 < S_N)
                attn[((size_t)b * S_N + s0) * D_N + h * HD_N + nt * 16 + n] =
                    f2bf(o0[nt][r] * linv0);
            if (s1 < S_N)
                attn[((size_t)b * S_N + s1) * D_N + h * HD_N + nt * 16 + n] =
                    f2bf(o1[nt][r] * linv1);
        }
    }
}

extern "C" void kernel_launch(void* const* d_in, const int* in_sizes, int n_in,
                              void* d_out, int out_size, void* d_ws, size_t ws_size,
                              hipStream_t stream) {
    const float* hs = (const float*)d_in[0];
    const float* fc = (const float*)d_in[1];
    const float* fs = (const float*)d_in[2];
    const float* Wq = (const float*)d_in[3];
    const float* bq = (const float*)d_in[4];
    const float* Wk = (const float*)d_in[5];
    const float* bk = (const float*)d_in[6];
    const float* Wv = (const float*)d_in[7];
    const float* bv = (const float*)d_in[8];
    const float* Wo = (const float*)d_in[9];
    const float* bo = (const float*)d_in[10];
    float* out = (float*)d_out;

    char* ws = (char*)d_ws;
    size_t off = 0;
    auto alloc = [&](size_t bytes) {
        char* p = ws + off; off += (bytes + 255) & ~(size_t)255; return p;
    };
    unsigned short* hsb  = (unsigned short*)alloc((size_t)M_PAD * K_N * 2); // aliased as 'at'
    unsigned short* qb   = (unsigned short*)alloc((size_t)M_N * K_N * 2 + 32768);
    unsigned short* kb   = (unsigned short*)alloc((size_t)M_N * K_N * 2 + 32768);
    unsigned short* vt   = (unsigned short*)alloc((size_t)B_N * H_N * HD_N * VT_S * 2);
    unsigned short* Wall = (unsigned short*)alloc((size_t)4 * D_N * K_N * 2);

    const int HS4 = M_N * K_N / 4;   // 2,954,240
    dim3 blk(256);

    cvt_kernel<<<(HS4 + 255) / 256, blk, 0, stream>>>(hs, hsb, HS4);
    cvt4_kernel<<<(4 * W4_N + 255) / 256, blk, 0, stream>>>(Wq, Wk, Wv, Wo, Wall);

    // fused QKV: 8-wave 128x128 (4 waves/SIMD), N = 3840 over [Wq;Wk;Wv]
    gemm8w_kernel<4><<<dim3(30, 73), dim3(512), 0, stream>>>(
        hsb, Wall, bq, bk, bv, fc, fs, qb, kb, vt);

    fattn_kernel<<<dim3(1280), blk, 0, stream>>>(qb, kb, vt, hsb /*= at*/);

    // out-projection: same 8-wave core, fp32 epilogue
    gemm8w_kernel<3><<<dim3(10, 73), dim3(512), 0, stream>>>(
        hsb, Wall + 3 * (size_t)D_N * K_N, bo, bo, bo, fc, fs, out, out, out);
}